// Round 1
// baseline (68.676 us; speedup 1.0000x reference)
//
#include <hip/hip_runtime.h>
#include <hip/hip_fp16.h>

#define NB 32
#define NTT 4096
#define ND 256
#define NK 64
#define TBROWS 128
#define THREADS 512

typedef __attribute__((ext_vector_type(8))) short short8;
typedef __attribute__((ext_vector_type(4))) float f32x4;

__device__ __forceinline__ unsigned short f2h(float f) {
    __half h = __float2half(f);
    return __half_as_ushort(h);
}

__device__ __forceinline__ short8 pack8(unsigned long long L, unsigned long long H) {
    union { unsigned long long q[2]; short8 s; } u;
    u.q[0] = L; u.q[1] = H;
    return u.s;
}

// ---- LDS geometry (all sizes in bytes) ----
// XR : [128 t][128 d] fp16 row-major, swizzled:   byte = t*256 + ((2d) ^ ((t&7)<<4))
// XT : [256 d][128 t] fp16 rotated:               byte = d*256 + ((2t + 8d) & 255)
// WT : [64 k][256 d]  fp16 row-major, swizzled:   byte = k*512 + ((2d) ^ ((k&7)<<4))
// AT : [64 k][128 t]  fp16 row-major, swizzled:   byte = k*256 + ((2t) ^ ((k&7)<<4))
// CS : [8 w][64 k] fp32 colsum exchange
#define XR_OFF 0
#define XT_OFF 32768
#define WT_OFF 98304
#define AT_OFF 131072
#define CS_OFF 147456
#define SM_BYTES 149504

__device__ __forceinline__ int xr_byte(int t, int d) { return XR_OFF + t*256 + ((2*d) ^ ((t & 7) << 4)); }
__device__ __forceinline__ int xt_byte(int d, int t) { return XT_OFF + d*256 + ((2*t + 8*d) & 255); }
__device__ __forceinline__ int wt_byte(int k, int d) { return WT_OFF + k*512 + ((2*d) ^ ((k & 7) << 4)); }
__device__ __forceinline__ int at_byte(int k, int t) { return AT_OFF + k*256 + ((2*t) ^ ((k & 7) << 4)); }

// Fused: logits = x@W + b ; A = softmax_k ; Spart += A^T @ x ; spart += colsum(A)
__global__ __launch_bounds__(THREADS) void nv_k1(const float* __restrict__ x,
                                                 const float* __restrict__ aw,
                                                 const float* __restrict__ ab,
                                                 float* __restrict__ Sp,
                                                 float* __restrict__ sp,
                                                 int P) {
    __shared__ char SM[SM_BYTES];
    const int tid  = threadIdx.x;
    const int w    = tid >> 6;        // wave 0..7
    const int lane = tid & 63;
    const int lo   = lane & 15;
    const int hi   = lane >> 4;
    const int wg   = blockIdx.x;
    const int b    = wg / P;
    const int p    = wg % P;
    const int rowsPer = NTT / P;
    const int nch  = rowsPer / TBROWS;

    // bias registers: bias[16*nt + lo]
    float biasr[4];
#pragma unroll
    for (int nt = 0; nt < 4; ++nt) biasr[nt] = ab[16 * nt + lo];

    // stage W^T (shared by all chunks): aw is [d][k], i = d*64 + k
#pragma unroll
    for (int it = 0; it < 32; ++it) {
        int i = it * THREADS + tid;
        int d = i >> 6;
        int k = i & 63;
        *(unsigned short*)(SM + wt_byte(k, d)) = f2h(aw[i]);
    }

    // S accumulator: wave w owns d-strip [32w, 32w+32), all 64 k rows
    f32x4 Sacc[4][2];
#pragma unroll
    for (int mt = 0; mt < 4; ++mt)
#pragma unroll
        for (int nt = 0; nt < 2; ++nt) Sacc[mt][nt] = (f32x4){0.f, 0.f, 0.f, 0.f};
    float csum[4] = {0.f, 0.f, 0.f, 0.f};

    for (int c = 0; c < nch; ++c) {
        const int t0 = p * rowsPer + c * TBROWS;

        // ---- stage: global -> fp16 -> XR(half0) + XT(full); half1 kept in regs ----
        unsigned int xh1[16];
        {
            const float* base = x + ((size_t)b * NTT + t0 + 16 * w) * ND;
#pragma unroll
            for (int ib = 0; ib < 4; ++ib) {
                unsigned short pk[4][4];
#pragma unroll
                for (int ii = 0; ii < 4; ++ii) {
                    int i = ib * 4 + ii;
                    const float* row = base + (size_t)i * ND;
                    float f0 = row[lane];
                    float f1 = row[lane + 64];
                    float f2 = row[lane + 128];
                    float f3 = row[lane + 192];
                    unsigned short u0 = f2h(f0), u1 = f2h(f1), u2 = f2h(f2), u3 = f2h(f3);
                    int t = 16 * w + i;
                    *(unsigned short*)(SM + xr_byte(t, lane))      = u0;
                    *(unsigned short*)(SM + xr_byte(t, lane + 64)) = u1;
                    xh1[i] = (unsigned int)u2 | ((unsigned int)u3 << 16);
                    pk[0][ii] = u0; pk[1][ii] = u1; pk[2][ii] = u2; pk[3][ii] = u3;
                }
#pragma unroll
                for (int q = 0; q < 4; ++q) {
                    int d = lane + 64 * q;
                    unsigned long long v = (unsigned long long)pk[q][0]
                                         | ((unsigned long long)pk[q][1] << 16)
                                         | ((unsigned long long)pk[q][2] << 32)
                                         | ((unsigned long long)pk[q][3] << 48);
                    *(unsigned long long*)(SM + xt_byte(d, 16 * w + 4 * ib)) = v;
                }
            }
        }
        __syncthreads();

        // ---- GEMM1 half0 (d 0..127): wave = t-strip [16w,16w+16), all 64 k ----
        f32x4 acc1[4];
#pragma unroll
        for (int nt = 0; nt < 4; ++nt) acc1[nt] = (f32x4){0.f, 0.f, 0.f, 0.f};
#pragma unroll
        for (int ds = 0; ds < 4; ++ds) {
            short8 a = *(const short8*)(SM + xr_byte(16 * w + lo, 32 * ds + 8 * hi));
#pragma unroll
            for (int nt = 0; nt < 4; ++nt) {
                short8 bw = *(const short8*)(SM + wt_byte(16 * nt + lo, 32 * ds + 8 * hi));
                acc1[nt] = __builtin_amdgcn_mfma_f32_16x16x32_f16(a, bw, acc1[nt], 0, 0, 0);
            }
        }
        __syncthreads();

        // ---- rewrite XR with d-half1 from registers ----
#pragma unroll
        for (int i = 0; i < 16; ++i) {
            int t = 16 * w + i;
            *(unsigned short*)(SM + xr_byte(t, lane))      = (unsigned short)(xh1[i] & 0xFFFFu);
            *(unsigned short*)(SM + xr_byte(t, lane + 64)) = (unsigned short)(xh1[i] >> 16);
        }
        __syncthreads();

        // ---- GEMM1 half1 (d 128..255) ----
#pragma unroll
        for (int ds = 0; ds < 4; ++ds) {
            short8 a = *(const short8*)(SM + xr_byte(16 * w + lo, 32 * ds + 8 * hi));
#pragma unroll
            for (int nt = 0; nt < 4; ++nt) {
                short8 bw = *(const short8*)(SM + wt_byte(16 * nt + lo, 128 + 32 * ds + 8 * hi));
                acc1[nt] = __builtin_amdgcn_mfma_f32_16x16x32_f16(a, bw, acc1[nt], 0, 0, 0);
            }
        }

        // ---- softmax over k (row t = 16w + 4hi + r ; col k = 16nt + lo) ----
        unsigned short abf[4][4];
#pragma unroll
        for (int r = 0; r < 4; ++r) {
            float v0 = acc1[0][r] + biasr[0];
            float v1 = acc1[1][r] + biasr[1];
            float v2 = acc1[2][r] + biasr[2];
            float v3 = acc1[3][r] + biasr[3];
            float m = fmaxf(fmaxf(v0, v1), fmaxf(v2, v3));
            m = fmaxf(m, __shfl_xor(m, 1));
            m = fmaxf(m, __shfl_xor(m, 2));
            m = fmaxf(m, __shfl_xor(m, 4));
            m = fmaxf(m, __shfl_xor(m, 8));
            float e0 = __expf(v0 - m), e1 = __expf(v1 - m);
            float e2 = __expf(v2 - m), e3 = __expf(v3 - m);
            float s = e0 + e1 + e2 + e3;
            s += __shfl_xor(s, 1);
            s += __shfl_xor(s, 2);
            s += __shfl_xor(s, 4);
            s += __shfl_xor(s, 8);
            float inv = 1.0f / s;
            e0 *= inv; e1 *= inv; e2 *= inv; e3 *= inv;
            csum[0] += e0; csum[1] += e1; csum[2] += e2; csum[3] += e3;
            abf[0][r] = f2h(e0); abf[1][r] = f2h(e1); abf[2][r] = f2h(e2); abf[3][r] = f2h(e3);
        }
        // write A^T to LDS: AT[k = 16nt+lo][t = 16w + 4hi + r], pairs of r
#pragma unroll
        for (int nt = 0; nt < 4; ++nt) {
#pragma unroll
            for (int rp = 0; rp < 4; rp += 2) {
                unsigned int v = (unsigned int)abf[nt][rp] | ((unsigned int)abf[nt][rp + 1] << 16);
                *(unsigned int*)(SM + at_byte(16 * nt + lo, 16 * w + 4 * hi + rp)) = v;
            }
        }
        __syncthreads();

        // ---- GEMM2: S[k][d] += sum_t A^T[k][t] * X[t][d]; wave d-strip [32w,32w+32) ----
#pragma unroll
        for (int ts = 0; ts < 4; ++ts) {
            short8 af[4];
#pragma unroll
            for (int mt = 0; mt < 4; ++mt)
                af[mt] = *(const short8*)(SM + at_byte(16 * mt + lo, 32 * ts + 8 * hi));
#pragma unroll
            for (int nt = 0; nt < 2; ++nt) {
                int d = 32 * w + 16 * nt + lo;
                unsigned long long L = *(const unsigned long long*)(SM + xt_byte(d, 32 * ts + 8 * hi));
                unsigned long long H = *(const unsigned long long*)(SM + xt_byte(d, 32 * ts + 8 * hi + 4));
                short8 bfr = pack8(L, H);
#pragma unroll
                for (int mt = 0; mt < 4; ++mt)
                    Sacc[mt][nt] = __builtin_amdgcn_mfma_f32_16x16x32_f16(af[mt], bfr, Sacc[mt][nt], 0, 0, 0);
            }
        }
        __syncthreads();
    }

    // ---- colsum: deterministic cross-wave reduce via LDS ----
    float* cs = (float*)(SM + CS_OFF);
#pragma unroll
    for (int nt = 0; nt < 4; ++nt) {
        float v = csum[nt];
        v += __shfl_xor(v, 16);
        v += __shfl_xor(v, 32);
        if (hi == 0) cs[w * 64 + 16 * nt + lo] = v;
    }
    __syncthreads();
    if (tid < 64) {
        float t = 0.f;
#pragma unroll
        for (int ww = 0; ww < 8; ++ww) t += cs[ww * 64 + tid];
        sp[(size_t)wg * 64 + tid] = t;
    }

    // ---- write partial S ----
#pragma unroll
    for (int mt = 0; mt < 4; ++mt)
#pragma unroll
        for (int nt = 0; nt < 2; ++nt)
#pragma unroll
            for (int r = 0; r < 4; ++r) {
                int kc = 16 * mt + 4 * hi + r;
                int d  = 32 * w + 16 * nt + lo;
                Sp[((size_t)wg * 64 + kc) * 256 + d] = Sacc[mt][nt][r];
            }
}

// Reduce partials, subtract colsum*centroid, L2-normalize per (b,k) row.
__global__ __launch_bounds__(256) void nv_k2(const float* __restrict__ Sp,
                                             const float* __restrict__ sp,
                                             const float* __restrict__ cent,
                                             float* __restrict__ out,
                                             int P) {
    const int bk = blockIdx.x;
    const int b  = bk >> 6;
    const int k  = bk & 63;
    const int d  = threadIdx.x;

    float s = 0.f;
    for (int p = 0; p < P; ++p)
        s += Sp[(((size_t)(b * P + p)) * 64 + k) * 256 + d];
    float cv = 0.f;
    for (int p = 0; p < P; ++p)
        cv += sp[(size_t)(b * P + p) * 64 + k];

    float v = s - cv * cent[k * 256 + d];

    float ss = v * v;
    ss += __shfl_xor(ss, 1);
    ss += __shfl_xor(ss, 2);
    ss += __shfl_xor(ss, 4);
    ss += __shfl_xor(ss, 8);
    ss += __shfl_xor(ss, 16);
    ss += __shfl_xor(ss, 32);
    __shared__ float red[4];
    const int wv = threadIdx.x >> 6, ln = threadIdx.x & 63;
    if (ln == 0) red[wv] = ss;
    __syncthreads();
    float tot = red[0] + red[1] + red[2] + red[3];
    float rn = 1.0f / fmaxf(sqrtf(tot), 1e-12f);
    out[((size_t)b * 64 + k) * 256 + d] = v * rn;
}

extern "C" void kernel_launch(void* const* d_in, const int* in_sizes, int n_in,
                              void* d_out, int out_size, void* d_ws, size_t ws_size,
                              hipStream_t stream) {
    (void)in_sizes; (void)n_in; (void)out_size;
    const float* x  = (const float*)d_in[0];
    const float* ct = (const float*)d_in[1];
    const float* aw = (const float*)d_in[2];
    const float* ab = (const float*)d_in[3];
    float* out = (float*)d_out;

    const size_t PSZ = (size_t)NB * NK * ND * sizeof(float);  // 2 MB per partial set
    int P = 0;
    const int cands[5] = {16, 8, 4, 2, 1};
    for (int i = 0; i < 5; ++i) {
        size_t need = (size_t)cands[i] * PSZ + (size_t)cands[i] * NB * NK * sizeof(float);
        if (need <= ws_size) { P = cands[i]; break; }
    }
    float* Sp;
    float* sp;
    if (P > 0) {
        Sp = (float*)d_ws;
        sp = (float*)((char*)d_ws + (size_t)P * PSZ);
    } else {
        // ultra-fallback: accumulate S directly in d_out (single writer per cell), colsums in ws
        P = 1;
        Sp = out;
        sp = (float*)d_ws;
    }

    nv_k1<<<dim3(NB * P), dim3(THREADS), 0, stream>>>(x, aw, ab, Sp, sp, P);
    nv_k2<<<dim3(NB * NK), dim3(256), 0, stream>>>(Sp, sp, ct, out, P);
}

// Round 2
// 61.337 us; speedup vs baseline: 1.1196x; 1.1196x over previous
//
#include <hip/hip_runtime.h>
#include <hip/hip_fp16.h>

#define NB 32
#define NTT 4096
#define ND 256
#define NK 64
#define CHUNK 64
#define THREADS 256

typedef __attribute__((ext_vector_type(8))) short short8;
typedef __attribute__((ext_vector_type(4))) float f32x4;

__device__ __forceinline__ unsigned short f2h(float f) {
    return __half_as_ushort(__float2half(f));
}

// ---- LDS layout (bytes) ----
// WT : [64 k][256 d] fp16 swizzled : byte = k*512 + ((2d) ^ ((k&7)<<4))   (32 KB)
// AT : 2 x [64 k][64 t] fp16 swizzled : k*128 + ((2t) ^ ((k&7)<<4))       (2 x 8 KB)
// CS : [4 w][64 k] f32 colsum exchange                                    (1 KB)
#define WT_OFF 0
#define AT_OFF 32768
#define CS_OFF 49152
#define SM_BYTES 50176

__device__ __forceinline__ int wt_byte(int k, int d) { return WT_OFF + k * 512 + ((2 * d) ^ ((k & 7) << 4)); }
__device__ __forceinline__ int at_byte(int buf, int k, int t) { return AT_OFF + buf * 8192 + k * 128 + ((2 * t) ^ ((k & 7) << 4)); }

__device__ __forceinline__ short8 cvt8(f32x4 a, f32x4 b) {
    short8 r;
    r[0] = (short)f2h(a[0]); r[1] = (short)f2h(a[1]);
    r[2] = (short)f2h(a[2]); r[3] = (short)f2h(a[3]);
    r[4] = (short)f2h(b[0]); r[5] = (short)f2h(b[1]);
    r[6] = (short)f2h(b[2]); r[7] = (short)f2h(b[3]);
    return r;
}

// Fused: logits = x@W + b ; A = softmax_k ; Spart += A^T @ x ; spart += colsum(A)
// X never touches LDS: GEMM1 A-fragments are per-lane row fragments loaded as
// float4 from global; GEMM2 B-fragments are per-lane column fragments re-read
// from global (L2-hot). LDS holds only W^T, double-buffered A^T, colsums.
__global__ __launch_bounds__(THREADS, 3) void nv_k1(const float* __restrict__ x,
                                                    const float* __restrict__ aw,
                                                    const float* __restrict__ ab,
                                                    float* __restrict__ Sp,
                                                    float* __restrict__ sp,
                                                    int P) {
    __shared__ char SM[SM_BYTES];
    const int tid  = threadIdx.x;
    const int w    = tid >> 6;        // wave 0..3
    const int lane = tid & 63;
    const int lo   = lane & 15;
    const int hi   = lane >> 4;
    const int wg   = blockIdx.x;
    const int b    = wg / P;
    const int p    = wg % P;
    const int rowsPer = NTT / P;
    const int nch  = rowsPer / CHUNK;

    // bias registers: bias for k = 16*nt + lo
    float biasr[4];
#pragma unroll
    for (int nt = 0; nt < 4; ++nt) biasr[nt] = ab[16 * nt + lo];

    // stage W^T: aw is [d][k] row-major, i = d*64 + k
#pragma unroll
    for (int it = 0; it < 64; ++it) {
        int i = it * THREADS + tid;
        int d = i >> 6;
        int k = i & 63;
        *(unsigned short*)(SM + wt_byte(k, d)) = f2h(aw[i]);
    }
    __syncthreads();

    // S accumulator: wave w owns d-strip [64w, 64w+64), all 64 k rows
    f32x4 Sacc[4][4];
#pragma unroll
    for (int mt = 0; mt < 4; ++mt)
#pragma unroll
        for (int nt = 0; nt < 4; ++nt) Sacc[mt][nt] = (f32x4){0.f, 0.f, 0.f, 0.f};
    float csum[4] = {0.f, 0.f, 0.f, 0.f};

    const float* xb = x + (size_t)b * NTT * ND;

    for (int c = 0; c < nch; ++c) {
        const int t0 = p * rowsPer + c * CHUNK;
        const int buf = c & 1;

        // ---- row-fragment loads: lane owns row t0 + 16w + lo, d-quarter hi ----
        const float* rowp = xb + (size_t)(t0 + 16 * w + lo) * ND;
        f32x4 rf[16];
#pragma unroll
        for (int ds = 0; ds < 8; ++ds) {
            rf[2 * ds]     = *(const f32x4*)(rowp + 32 * ds + 8 * hi);
            rf[2 * ds + 1] = *(const f32x4*)(rowp + 32 * ds + 8 * hi + 4);
        }

        // ---- GEMM1: L[t][k], t-strip [16w,16w+16), reduction d (8 slices of 32) ----
        f32x4 acc1[4];
#pragma unroll
        for (int nt = 0; nt < 4; ++nt) acc1[nt] = (f32x4){0.f, 0.f, 0.f, 0.f};
#pragma unroll
        for (int ds = 0; ds < 8; ++ds) {
            short8 a = cvt8(rf[2 * ds], rf[2 * ds + 1]);
#pragma unroll
            for (int nt = 0; nt < 4; ++nt) {
                short8 bw = *(const short8*)(SM + wt_byte(16 * nt + lo, 32 * ds + 8 * hi));
                acc1[nt] = __builtin_amdgcn_mfma_f32_16x16x32_f16(a, bw, acc1[nt], 0, 0, 0);
            }
        }

        // ---- issue GEMM2 column-fragment loads, t-slice 0 (hidden under softmax) ----
        // lane needs X[t0 + 32*ts + 8hi + j][64w + 16nt + lo]
        float ca0[4][8];
#pragma unroll
        for (int nt = 0; nt < 4; ++nt)
#pragma unroll
            for (int j = 0; j < 8; ++j)
                ca0[nt][j] = xb[(size_t)(t0 + 8 * hi + j) * ND + 64 * w + 16 * nt + lo];

        // ---- softmax over k (row t = 16w + 4hi + r ; col k = 16nt + lo) ----
        unsigned short abf[4][4];
#pragma unroll
        for (int r = 0; r < 4; ++r) {
            float v0 = acc1[0][r] + biasr[0];
            float v1 = acc1[1][r] + biasr[1];
            float v2 = acc1[2][r] + biasr[2];
            float v3 = acc1[3][r] + biasr[3];
            float m = fmaxf(fmaxf(v0, v1), fmaxf(v2, v3));
            m = fmaxf(m, __shfl_xor(m, 1));
            m = fmaxf(m, __shfl_xor(m, 2));
            m = fmaxf(m, __shfl_xor(m, 4));
            m = fmaxf(m, __shfl_xor(m, 8));
            float e0 = __expf(v0 - m), e1 = __expf(v1 - m);
            float e2 = __expf(v2 - m), e3 = __expf(v3 - m);
            float s = e0 + e1 + e2 + e3;
            s += __shfl_xor(s, 1);
            s += __shfl_xor(s, 2);
            s += __shfl_xor(s, 4);
            s += __shfl_xor(s, 8);
            float inv = 1.0f / s;
            e0 *= inv; e1 *= inv; e2 *= inv; e3 *= inv;
            csum[0] += e0; csum[1] += e1; csum[2] += e2; csum[3] += e3;
            abf[0][r] = f2h(e0); abf[1][r] = f2h(e1); abf[2][r] = f2h(e2); abf[3][r] = f2h(e3);
        }
        // write A^T: AT[k = 16nt+lo][t = 16w + 4hi + r], pairs of r -> dword
#pragma unroll
        for (int nt = 0; nt < 4; ++nt) {
#pragma unroll
            for (int rp = 0; rp < 4; rp += 2) {
                unsigned int v = (unsigned int)abf[nt][rp] | ((unsigned int)abf[nt][rp + 1] << 16);
                *(unsigned int*)(SM + at_byte(buf, 16 * nt + lo, 16 * w + 4 * hi + rp)) = v;
            }
        }
        __syncthreads();   // the ONLY barrier per chunk: A^T visible to all waves

        // ---- issue column-fragment loads, t-slice 1 (hidden under GEMM2 slice 0) ----
        float ca1[4][8];
#pragma unroll
        for (int nt = 0; nt < 4; ++nt)
#pragma unroll
            for (int j = 0; j < 8; ++j)
                ca1[nt][j] = xb[(size_t)(t0 + 32 + 8 * hi + j) * ND + 64 * w + 16 * nt + lo];

        // ---- GEMM2: S[k][d] += sum_t A^T[k][t] X[t][d]; wave d-strip [64w,64w+64) ----
        {
            short8 af[4];
#pragma unroll
            for (int mt = 0; mt < 4; ++mt)
                af[mt] = *(const short8*)(SM + at_byte(buf, 16 * mt + lo, 8 * hi));
#pragma unroll
            for (int nt = 0; nt < 4; ++nt) {
                short8 bf;
#pragma unroll
                for (int j = 0; j < 8; ++j) bf[j] = (short)f2h(ca0[nt][j]);
#pragma unroll
                for (int mt = 0; mt < 4; ++mt)
                    Sacc[mt][nt] = __builtin_amdgcn_mfma_f32_16x16x32_f16(af[mt], bf, Sacc[mt][nt], 0, 0, 0);
            }
#pragma unroll
            for (int mt = 0; mt < 4; ++mt)
                af[mt] = *(const short8*)(SM + at_byte(buf, 16 * mt + lo, 32 + 8 * hi));
#pragma unroll
            for (int nt = 0; nt < 4; ++nt) {
                short8 bf;
#pragma unroll
                for (int j = 0; j < 8; ++j) bf[j] = (short)f2h(ca1[nt][j]);
#pragma unroll
                for (int mt = 0; mt < 4; ++mt)
                    Sacc[mt][nt] = __builtin_amdgcn_mfma_f32_16x16x32_f16(af[mt], bf, Sacc[mt][nt], 0, 0, 0);
            }
        }
    }

    // ---- colsum: deterministic cross-wave reduce via LDS ----
    __syncthreads();
    float* cs = (float*)(SM + CS_OFF);
#pragma unroll
    for (int nt = 0; nt < 4; ++nt) {
        float v = csum[nt];
        v += __shfl_xor(v, 16);
        v += __shfl_xor(v, 32);
        if (hi == 0) cs[w * 64 + 16 * nt + lo] = v;
    }
    __syncthreads();
    if (tid < 64) {
        float t = 0.f;
#pragma unroll
        for (int ww = 0; ww < 4; ++ww) t += cs[ww * 64 + tid];
        sp[(size_t)wg * 64 + tid] = t;
    }

    // ---- write partial S: k = 16mt + 4hi + r, d = 64w + 16nt + lo ----
#pragma unroll
    for (int mt = 0; mt < 4; ++mt)
#pragma unroll
        for (int nt = 0; nt < 4; ++nt)
#pragma unroll
            for (int r = 0; r < 4; ++r) {
                int kc = 16 * mt + 4 * hi + r;
                int d  = 64 * w + 16 * nt + lo;
                Sp[((size_t)wg * 64 + kc) * 256 + d] = Sacc[mt][nt][r];
            }
}

// Reduce partials, subtract colsum*centroid, L2-normalize per (b,k) row.
__global__ __launch_bounds__(256) void nv_k2(const float* __restrict__ Sp,
                                             const float* __restrict__ sp,
                                             const float* __restrict__ cent,
                                             float* __restrict__ out,
                                             int P) {
    const int bk = blockIdx.x;
    const int b  = bk >> 6;
    const int k  = bk & 63;
    const int d  = threadIdx.x;

    float s = 0.f;
    for (int p = 0; p < P; ++p)
        s += Sp[(((size_t)(b * P + p)) * 64 + k) * 256 + d];
    float cv = 0.f;
    for (int p = 0; p < P; ++p)
        cv += sp[(size_t)(b * P + p) * 64 + k];

    float v = s - cv * cent[k * 256 + d];

    float ss = v * v;
    ss += __shfl_xor(ss, 1);
    ss += __shfl_xor(ss, 2);
    ss += __shfl_xor(ss, 4);
    ss += __shfl_xor(ss, 8);
    ss += __shfl_xor(ss, 16);
    ss += __shfl_xor(ss, 32);
    __shared__ float red[4];
    const int wv = threadIdx.x >> 6, ln = threadIdx.x & 63;
    if (ln == 0) red[wv] = ss;
    __syncthreads();
    float tot = red[0] + red[1] + red[2] + red[3];
    float rn = 1.0f / fmaxf(sqrtf(tot), 1e-12f);
    out[((size_t)b * 64 + k) * 256 + d] = v * rn;
}

extern "C" void kernel_launch(void* const* d_in, const int* in_sizes, int n_in,
                              void* d_out, int out_size, void* d_ws, size_t ws_size,
                              hipStream_t stream) {
    (void)in_sizes; (void)n_in; (void)out_size;
    const float* x  = (const float*)d_in[0];
    const float* ct = (const float*)d_in[1];
    const float* aw = (const float*)d_in[2];
    const float* ab = (const float*)d_in[3];
    float* out = (float*)d_out;

    const size_t PSZ = (size_t)NB * NK * ND * sizeof(float);  // 2 MB per partial set
    int P = 0;
    const int cands[5] = {16, 8, 4, 2, 1};
    for (int i = 0; i < 5; ++i) {
        size_t need = (size_t)cands[i] * PSZ + (size_t)cands[i] * NB * NK * sizeof(float);
        if (need <= ws_size) { P = cands[i]; break; }
    }
    float* Sp;
    float* sp;
    if (P > 0) {
        Sp = (float*)d_ws;
        sp = (float*)((char*)d_ws + (size_t)P * PSZ);
    } else {
        P = 1;
        Sp = out;
        sp = (float*)d_ws;
    }

    nv_k1<<<dim3(NB * P), dim3(THREADS), 0, stream>>>(x, aw, ab, Sp, sp, P);
    nv_k2<<<dim3(NB * NK), dim3(256), 0, stream>>>(Sp, sp, ct, out, P);
}